// Round 6
// baseline (498.133 us; speedup 1.0000x reference)
//
#include <hip/hip_runtime.h>

// IterNorm (group whitening, Newton-Schulz) for x:(64,256,56,56) fp32, G=32, T=5.
// Stage 1 (k_gram): coalesced reg-staged loads -> bf16 LDS tile -> MFMA partial Gram;
//                   also zeroes the per-sample ready-flags used by the fused stage 2+3.
// Stage 2+3 (k_apply): NS fused into apply. Blocks 0..63 (dispatched first -> resident
//                   first, no deadlock) compute sigma + Newton-Schulz for sample n,
//                   publish wmT/off (threadfence + agent-release flag), then do one
//                   apply chunk. Blocks 64.. prefetch x, spin on agent-acquire flag,
//                   pull wm via agent-scope atomic loads into LDS, apply, nt-store.

#define HW 3136
#define NCH 256

typedef __attribute__((ext_vector_type(8)))  short bf16x8;
typedef __attribute__((ext_vector_type(16))) float f32x16;
typedef __attribute__((ext_vector_type(2)))  float f32x2;

__device__ __forceinline__ short f2bf(float f) {
    unsigned u = __builtin_bit_cast(unsigned, f);
    unsigned r = (u + 0x7FFFu + ((u >> 16) & 1u)) >> 16;   // RNE
    return (short)r;
}

// ---------------- Stage 1: partial Gram + partial channel sums ----------------
// Grid 512 = (n, cl); block 256 = 4 waves. Wave w handles hw tiles t = w, w+4, ... < 49,
// tile = 32 groups x 64 hw. LDS tile: bf16, 136B row stride -> conflict-free b64 frags.
__global__ __launch_bounds__(256) void k_gram(const float* __restrict__ x,
                                              float* __restrict__ gramPart,
                                              float* __restrict__ sxPart,
                                              int* __restrict__ flags) {
    __shared__ uint2 stage[4][32 * 17];      // per-wave bf16 tile 32 x 64 (+8B row pad)
    __shared__ float gred[4][1024];
    __shared__ float sred[4][32][16];

    const int w    = threadIdx.x >> 6;
    const int lane = threadIdx.x & 63;
    const int n    = blockIdx.x >> 3;
    const int cl   = blockIdx.x & 7;
    const int qr   = lane >> 4;     // sub-row within a load instruction (0..3)
    const int c16  = lane & 15;     // float4 column index (0..15)
    const int frow = lane & 31;     // MFMA fragment row (group)
    const int half = lane >> 5;     // MFMA fragment k-half

    // zero the ready-flag for this sample (consumed by fused apply next dispatch;
    // dispatch-boundary coherence makes this visible regardless of ws poison state)
    if (cl == 0 && threadIdx.x == 0) flags[n] = 0;

    uint2* st = stage[w];

    // element addr for instr j, tile t: gbase + j*(32*HW) + t*64
    const float* gbase = x + ((size_t)(n * NCH + cl) + (size_t)qr * 8) * HW + c16 * 4;

    f32x16 acc;
    #pragma unroll
    for (int i = 0; i < 16; i++) acc[i] = 0.0f;
    float sreg[8];
    #pragma unroll
    for (int j = 0; j < 8; j++) sreg[j] = 0.0f;

    float4 v[8];
    int t = w;
    #pragma unroll
    for (int j = 0; j < 8; j++)
        v[j] = *(const float4*)(gbase + (size_t)j * (32 * HW) + t * 64);

    while (true) {
        // convert + LDS write + per-channel partial sums (channel g = 4j + qr)
        #pragma unroll
        for (int j = 0; j < 8; j++) {
            uint2 pk;
            pk.x = (unsigned)(unsigned short)f2bf(v[j].x) |
                   ((unsigned)(unsigned short)f2bf(v[j].y) << 16);
            pk.y = (unsigned)(unsigned short)f2bf(v[j].z) |
                   ((unsigned)(unsigned short)f2bf(v[j].w) << 16);
            st[(4 * j + qr) * 17 + c16] = pk;
            sreg[j] += (v[j].x + v[j].y) + (v[j].z + v[j].w);
        }
        const int tn = t + 4;
        const bool more = (tn < 49);
        if (more) {
            #pragma unroll
            for (int j = 0; j < 8; j++)
                v[j] = *(const float4*)(gbase + (size_t)j * (32 * HW) + tn * 64);
        }
        // fragment reads + MFMA (same-wave ds_write->ds_read order is safe; no barrier)
        #pragma unroll
        for (int k = 0; k < 4; k++) {
            const int idx = frow * 17 + k * 4 + half * 2;
            uint2 q0 = st[idx];
            uint2 q1 = st[idx + 1];
            uint4 qq = make_uint4(q0.x, q0.y, q1.x, q1.y);
            bf16x8 f = __builtin_bit_cast(bf16x8, qq);
            acc = __builtin_amdgcn_mfma_f32_32x32x16_bf16(f, f, acc, 0, 0, 0);
        }
        if (!more) break;
        t = tn;
    }

    // block-level reduce: 4 waves -> one 32x32 partial Gram + 32 channel sums
    #pragma unroll
    for (int t16 = 0; t16 < 16; t16++) {
        const int row = (t16 & 3) + 8 * (t16 >> 2) + 4 * half;  // C/D layout (verified)
        gred[w][row * 32 + frow] = acc[t16];
    }
    #pragma unroll
    for (int j = 0; j < 8; j++) sred[w][4 * j + qr][c16] = sreg[j];
    __syncthreads();

    const int tid = threadIdx.x;
    for (int e = tid; e < 1024; e += 256) {
        float s = gred[0][e] + gred[1][e] + gred[2][e] + gred[3][e];
        gramPart[(size_t)blockIdx.x * 1024 + e] = s;
    }
    if (tid < 32) {
        float s = 0.0f;
        #pragma unroll
        for (int ww = 0; ww < 4; ww++)
            #pragma unroll
            for (int c = 0; c < 16; c++) s += sred[ww][tid][c];
        sxPart[(size_t)blockIdx.x * 32 + tid] = s;
    }
}

// ---------------- mm256: D = X @ Y, X symmetric, 256 threads ----------------
__device__ __forceinline__ void mm256(float* __restrict__ D, const float* __restrict__ X,
                                      const float* __restrict__ Y, int r, int c4) {
    float c0 = 0.0f, c1 = 0.0f, c2 = 0.0f, c3 = 0.0f;
    #pragma unroll
    for (int k = 0; k < 32; k++) {
        const float a = X[k * 32 + r];
        const float4 y = *(const float4*)(Y + k * 32 + c4 * 4);
        c0 = fmaf(a, y.x, c0); c1 = fmaf(a, y.y, c1);
        c2 = fmaf(a, y.z, c2); c3 = fmaf(a, y.w, c3);
    }
    float4 o = { c0, c1, c2, c3 };
    *(float4*)(D + r * 32 + c4 * 4) = o;
}

// ---------------- Stage 2+3: fused NS + apply ----------------
// bid < 64: designated block for sample n=bid (rb=0): NS -> publish wm -> apply chunk.
// bid >= 64: b=bid-64, n=b/48, rb=1+b%48: prefetch x, wait flag, apply chunk.
__global__ __launch_bounds__(256) void k_apply(const float* __restrict__ x,
                                               const float* __restrict__ gramPart,
                                               const float* __restrict__ sxPart,
                                               float* __restrict__ wmT,
                                               float* __restrict__ offG,
                                               int* __restrict__ flags,
                                               const float* __restrict__ weight,
                                               const float* __restrict__ bias,
                                               float* __restrict__ out) {
    __shared__ __align__(16) float sig[1024];
    __shared__ __align__(16) float P[1024];
    __shared__ __align__(16) float A[1024];
    __shared__ __align__(16) float B[1024];
    __shared__ __align__(16) float wmS[1024];
    __shared__ float offS[32];
    __shared__ float meanS[32];
    __shared__ float tiS;

    const int bid = blockIdx.x;
    const int t   = threadIdx.x;
    int n, rb;
    if (bid < 64) { n = bid; rb = 0; }
    else { const int b = bid - 64; n = b / 48; rb = 1 + b % 48; }

    const int idx = rb * 256 + t;              // 0..12543
    const int cl  = idx / 1568;
    const int hw  = (idx % 1568) * 2;

    // ---- issue x prefetch (stays in flight during NS / spin) ----
    const float* xb = x + (size_t)n * NCH * HW + cl * HW + hw;
    f32x2 xv[32];
    #pragma unroll
    for (int h = 0; h < 32; h++)
        xv[h] = *(const f32x2*)(xb + (size_t)h * 8 * HW);

    if (rb == 0) {
        // ================= Newton-Schulz for sample n =================
        if (t < 32) {
            float s = 0.0f;
            #pragma unroll
            for (int c = 0; c < 8; c++) s += sxPart[((size_t)n * 8 + c) * 32 + t];
            meanS[t] = s * (1.0f / 25088.0f);
        }
        __syncthreads();

        for (int e = t; e < 1024; e += 256) {
            float s = 0.0f;
            #pragma unroll
            for (int p = 0; p < 8; p++) s += gramPart[((size_t)n * 8 + p) * 1024 + e];
            sig[e] = s * (1.0f / 25088.0f) - meanS[e >> 5] * meanS[e & 31];
        }
        __syncthreads();

        if (t < 64) {
            float d = (t < 32) ? sig[t * 33] : 0.0f;
            #pragma unroll
            for (int o = 16; o > 0; o >>= 1) d += __shfl_down(d, o);
            if (t == 0) tiS = 1.0f / d;
        }
        __syncthreads();
        const float ti = tiS;
        for (int e = t; e < 1024; e += 256) {
            sig[e] *= ti;
            P[e] = ((e >> 5) == (e & 31)) ? 1.0f : 0.0f;
        }
        __syncthreads();

        const int r  = t >> 3;
        const int c4 = t & 7;
        for (int it = 0; it < 5; it++) {
            mm256(A, P, P, r, c4);   __syncthreads();   // A = P^2
            mm256(B, A, P, r, c4);   __syncthreads();   // B = P^3
            mm256(A, B, sig, r, c4); __syncthreads();   // A = P^3 @ sigma_n
            for (int e = t; e < 1024; e += 256) P[e] = 1.5f * P[e] - 0.5f * A[e];
            __syncthreads();
        }

        const float sti = sqrtf(ti);
        // fill local wmS (transposed: wmS[h*32+g] = wm[g][h]) and publish to global
        for (int e = t; e < 1024; e += 256) {
            const float v = P[(e & 31) * 32 + (e >> 5)] * sti;
            wmS[e] = v;
            wmT[(size_t)n * 1024 + e] = v;
        }
        if (t < 32) {
            float s = 0.0f;
            #pragma unroll
            for (int h = 0; h < 32; h++) s += P[t * 32 + h] * meanS[h];
            const float ov = s * sti;
            offS[t] = ov;
            offG[n * 32 + t] = ov;
        }
        __syncthreads();
        // make wmT/offG visible device-wide, then release the flag
        __threadfence();
        if (t == 0)
            __hip_atomic_store(&flags[n], 1, __ATOMIC_RELEASE, __HIP_MEMORY_SCOPE_AGENT);
    } else {
        // ================= wait for sample n's wm =================
        if (t == 0) {
            while (__hip_atomic_load(&flags[n], __ATOMIC_ACQUIRE,
                                     __HIP_MEMORY_SCOPE_AGENT) == 0)
                __builtin_amdgcn_s_sleep(8);
        }
        __syncthreads();
        // coherent (agent-scope) pulls of wm/off into LDS — immune to stale L1/L2
        for (int e = t; e < 1024; e += 256)
            wmS[e] = __hip_atomic_load(&wmT[(size_t)n * 1024 + e],
                                       __ATOMIC_RELAXED, __HIP_MEMORY_SCOPE_AGENT);
        if (t < 32)
            offS[t] = __hip_atomic_load(&offG[n * 32 + t],
                                        __ATOMIC_RELAXED, __HIP_MEMORY_SCOPE_AGENT);
        __syncthreads();
    }

    // ================= apply: s[g] = sum_h wm[g][h] * x[h] =================
    f32x2 s[32];
    #pragma unroll
    for (int g = 0; g < 32; g++) { s[g][0] = 0.0f; s[g][1] = 0.0f; }

    #pragma unroll 4
    for (int h = 0; h < 32; h++) {
        const f32x2 xvh = xv[h];
        const float* wrow = &wmS[h * 32];
        #pragma unroll
        for (int g4 = 0; g4 < 8; g4++) {
            const float4 a4 = *(const float4*)(wrow + g4 * 4);   // LDS broadcast
            s[g4*4+0][0] = fmaf(a4.x, xvh[0], s[g4*4+0][0]);
            s[g4*4+0][1] = fmaf(a4.x, xvh[1], s[g4*4+0][1]);
            s[g4*4+1][0] = fmaf(a4.y, xvh[0], s[g4*4+1][0]);
            s[g4*4+1][1] = fmaf(a4.y, xvh[1], s[g4*4+1][1]);
            s[g4*4+2][0] = fmaf(a4.z, xvh[0], s[g4*4+2][0]);
            s[g4*4+2][1] = fmaf(a4.z, xvh[1], s[g4*4+2][1]);
            s[g4*4+3][0] = fmaf(a4.w, xvh[0], s[g4*4+3][0]);
            s[g4*4+3][1] = fmaf(a4.w, xvh[1], s[g4*4+3][1]);
        }
    }

    float* ob = out + (size_t)n * NCH * HW + cl * HW + hw;
    #pragma unroll
    for (int g = 0; g < 32; g++) {
        const int c = g * 8 + cl;
        const float wv = weight[c];
        const float bv = bias[c];
        const float o  = offS[g];
        f32x2 r;
        r[0] = fmaf(s[g][0] - o, wv, bv);
        r[1] = fmaf(s[g][1] - o, wv, bv);
        __builtin_nontemporal_store(r, (f32x2*)(ob + (size_t)g * 8 * HW));
    }
}

extern "C" void kernel_launch(void* const* d_in, const int* in_sizes, int n_in,
                              void* d_out, int out_size, void* d_ws, size_t ws_size,
                              hipStream_t stream) {
    const float* x      = (const float*)d_in[0];
    const float* weight = (const float*)d_in[1];
    const float* bias   = (const float*)d_in[2];
    float* out = (float*)d_out;

    // ws (floats): gramPart 512*1024 | sxPart 512*32 | wmT 64*1024 | off 64*32 | flags 64
    float* ws       = (float*)d_ws;
    float* gramPart = ws;
    float* sxPart   = gramPart + (size_t)512 * 1024;
    float* wmT      = sxPart + (size_t)512 * 32;
    float* offG     = wmT + (size_t)64 * 1024;
    int*   flags    = (int*)(offG + (size_t)64 * 32);

    hipLaunchKernelGGL(k_gram,  dim3(512),  dim3(256), 0, stream, x, gramPart, sxPart, flags);
    hipLaunchKernelGGL(k_apply, dim3(3136), dim3(256), 0, stream, x, gramPart, sxPart,
                       wmT, offG, flags, weight, bias, out);
}